// Round 3
// baseline (304.112 us; speedup 1.0000x reference)
//
#include <hip/hip_runtime.h>

// KL-style loss: mean_n [ -sum_y target[n,y] * log_softmax(pred)[n,y] ]
// N = 4194304 rows, C = 10, fp32 in, scalar fp32 out.
//
// Identity: loss_total = sum_n [ st_n * lse_n ] - sum_{n,y} t*x
//
// R8 = R7's all-vector LDS row-gather + R5's single-buffer occupancy.
//   R7 (two 20KB buffers, 1 barrier): 4 blocks/CU = 16 waves/CU.
//   R8 (one 20KB buffer reused pred->tgt, 3 barriers): 8 blocks/CU =
//   32 waves/CU (the per-CU wave cap) -> 2x the HBM loads in flight for
//   latency hiding on the 900-cycle stream. Barriers are per-block
//   (4 waves) and cheap. LDS traffic stays all-b128: 5 writes + 5 reads
//   per array per thread, conflict-neutral (64 lanes x 16B over 5120B
//   spans all 32 banks 8-deep = the size floor).

#define N_ROWS 4194304
#define C_DIM 10
#define BLOCK 256
#define ROWS_PER_BLOCK 512                        // 2 rows per thread
#define F4_PER_THREAD 5                           // 512*10/4/256
#define F4_PER_BLOCK (ROWS_PER_BLOCK * C_DIM / 4) // 1280
#define NBLOCKS (N_ROWS / ROWS_PER_BLOCK)         // 8192
#define RBLOCK 1024

typedef float v4f __attribute__((ext_vector_type(4)));

__global__ __launch_bounds__(BLOCK) void kl_loss_kernel(
    const float* __restrict__ pred,
    const float* __restrict__ tgt,
    float* __restrict__ partial)   // NBLOCKS floats
{
    __shared__ v4f sa[F4_PER_BLOCK];   // 20 KB, reused pred -> tgt
    __shared__ float sred[BLOCK / 64];

    const int tid = threadIdx.x;
    const size_t blk_f4 = (size_t)blockIdx.x * F4_PER_BLOCK;

    const v4f* p4 = reinterpret_cast<const v4f*>(pred);
    const v4f* t4 = reinterpret_cast<const v4f*>(tgt);

    // ---- Phase 1: perfectly coalesced loads (1024B/wave-instruction) ----
    v4f pv[F4_PER_THREAD], tv[F4_PER_THREAD];
#pragma unroll
    for (int i = 0; i < F4_PER_THREAD; ++i)
        pv[i] = __builtin_nontemporal_load(&p4[blk_f4 + i * BLOCK + tid]);
#pragma unroll
    for (int i = 0; i < F4_PER_THREAD; ++i)
        tv[i] = __builtin_nontemporal_load(&t4[blk_f4 + i * BLOCK + tid]);

    // global dot term straight from registers (no row structure needed)
    float dot = 0.0f;
#pragma unroll
    for (int i = 0; i < F4_PER_THREAD; ++i)
#pragma unroll
        for (int c = 0; c < 4; ++c)
            dot = fmaf(tv[i][c], pv[i][c], dot);

    // ---- Phase 2: pred through LDS (vector), 2 whole rows per thread ----
#pragma unroll
    for (int i = 0; i < F4_PER_THREAD; ++i)
        sa[i * BLOCK + tid] = pv[i];
    __syncthreads();

    const v4f* rr = reinterpret_cast<const v4f*>(
        reinterpret_cast<const float*>(sa) + 20 * tid);   // byte 80*tid, 16B-aligned

    float x[2 * C_DIM];
#pragma unroll
    for (int i = 0; i < F4_PER_THREAD; ++i) {
        v4f a = rr[i];
#pragma unroll
        for (int c = 0; c < 4; ++c) x[i * 4 + c] = a[c];
    }

    float lse[2];
#pragma unroll
    for (int half = 0; half < 2; ++half) {
        const int o = half * C_DIM;
        float m = x[o];
#pragma unroll
        for (int y = 1; y < C_DIM; ++y) m = fmaxf(m, x[o + y]);
        float s = 0.0f;
#pragma unroll
        for (int y = 0; y < C_DIM; ++y) s += __expf(x[o + y] - m);
        lse[half] = m + __logf(s);
    }
    __syncthreads();   // all pred row-reads done before overwrite

    // ---- Phase 3: tgt through the SAME buffer ----
#pragma unroll
    for (int i = 0; i < F4_PER_THREAD; ++i)
        sa[i * BLOCK + tid] = tv[i];
    __syncthreads();

    float acc = -dot;
#pragma unroll
    for (int half = 0; half < 2; ++half) {
        float st = 0.0f;
        // rows of this thread start at f4 index 5*tid; halves are
        // f4 [5t..5t+1]+2 floats of [5t+2] and the rest.
        // Simpler: read the 5 f4s once and sum per-half by word index.
        if (half == 0) {
            v4f a0 = rr[0], a1 = rr[1], a2 = rr[2];
            st = a0[0] + a0[1] + a0[2] + a0[3]
               + a1[0] + a1[1] + a1[2] + a1[3]
               + a2[0] + a2[1];
            acc = fmaf(st, lse[0], acc);
        } else {
            v4f a2 = rr[2], a3 = rr[3], a4 = rr[4];
            st = a2[2] + a2[3]
               + a3[0] + a3[1] + a3[2] + a3[3]
               + a4[0] + a4[1] + a4[2] + a4[3];
            acc = fmaf(st, lse[1], acc);
        }
    }

    // ---- Reduction: wave shuffle -> LDS -> one store per block ----
#pragma unroll
    for (int off = 32; off > 0; off >>= 1)
        acc += __shfl_down(acc, off, 64);

    const int lane = tid & 63;
    const int wid  = tid >> 6;
    if (lane == 0) sred[wid] = acc;
    __syncthreads();

    if (tid == 0)
        partial[blockIdx.x] = sred[0] + sred[1] + sred[2] + sred[3];
}

// ---------------- final reduce: one block over NBLOCKS partials ----------------
__global__ __launch_bounds__(RBLOCK) void kl_reduce_kernel(
    const float* __restrict__ partial,
    float* __restrict__ out)
{
    __shared__ float sred[RBLOCK / 64];
    const int tid = threadIdx.x;

    float acc = 0.0f;
#pragma unroll
    for (int i = 0; i < NBLOCKS / RBLOCK; ++i)
        acc += partial[i * RBLOCK + tid];

#pragma unroll
    for (int off = 32; off > 0; off >>= 1)
        acc += __shfl_down(acc, off, 64);

    const int lane = tid & 63;
    const int wid  = tid >> 6;
    if (lane == 0) sred[wid] = acc;
    __syncthreads();

    if (tid == 0) {
        float b = 0.0f;
#pragma unroll
        for (int i = 0; i < RBLOCK / 64; ++i) b += sred[i];
        out[0] = b * (1.0f / (float)N_ROWS);
    }
}

extern "C" void kernel_launch(void* const* d_in, const int* in_sizes, int n_in,
                              void* d_out, int out_size, void* d_ws, size_t ws_size,
                              hipStream_t stream)
{
    const float* pred = (const float*)d_in[0];
    const float* tgt  = (const float*)d_in[1];
    float* out = (float*)d_out;
    float* partialbuf = (float*)d_ws;

    kl_loss_kernel<<<NBLOCKS, BLOCK, 0, stream>>>(pred, tgt, partialbuf);
    kl_reduce_kernel<<<1, RBLOCK, 0, stream>>>(partialbuf, out);
}

// Round 4
// 303.041 us; speedup vs baseline: 1.0035x; 1.0035x over previous
//
#include <hip/hip_runtime.h>

// KL-style loss: mean_n [ -sum_y target[n,y] * log_softmax(pred)[n,y] ]
// N = 4194304 rows, C = 10, fp32 in, scalar fp32 out.
//
// Identity: loss_total = sum_n [ st_n * lse_n ] - sum_{n,y} t*x
//
// R9 = R7 (best: two 20KB tiles, all-b128 LDS row-gather, 1 barrier)
//      minus the cross-wave epilogue.
//   R8 lesson: single-buffer/3-barrier cost 4 us; occupancy was not the
//   limiter. Here instead: drop sred entirely -> LDS = exactly 40960 B
//   (was 40976) -> 4 blocks/CU instead of 3, and the epilogue is just a
//   64-lane shuffle + one store per wave (partial[blk*4+wid]), no barrier,
//   no serial sum. Reduce kernel absorbs 32768 partials (32 loads/thread).

#define N_ROWS 4194304
#define C_DIM 10
#define BLOCK 256
#define ROWS_PER_BLOCK 512                        // 2 rows per thread
#define F4_PER_THREAD 5                           // 512*10/4/256
#define F4_PER_BLOCK (ROWS_PER_BLOCK * C_DIM / 4) // 1280
#define NBLOCKS (N_ROWS / ROWS_PER_BLOCK)         // 8192
#define NPARTIAL (NBLOCKS * 4)                    // one per wave
#define RBLOCK 1024

typedef float v4f __attribute__((ext_vector_type(4)));

__global__ __launch_bounds__(BLOCK) void kl_loss_kernel(
    const float* __restrict__ pred,
    const float* __restrict__ tgt,
    float* __restrict__ partial)   // NPARTIAL floats
{
    __shared__ v4f sa[F4_PER_BLOCK];   // pred tile, 20 KB
    __shared__ v4f sb[F4_PER_BLOCK];   // tgt tile, 20 KB   (total exactly 40 KB)

    const int tid = threadIdx.x;
    const size_t blk_f4 = (size_t)blockIdx.x * F4_PER_BLOCK;

    const v4f* p4 = reinterpret_cast<const v4f*>(pred);
    const v4f* t4 = reinterpret_cast<const v4f*>(tgt);

    // ---- Phase 1: perfectly coalesced loads (1024B/wave-instruction) ----
    v4f pv[F4_PER_THREAD], tv[F4_PER_THREAD];
#pragma unroll
    for (int i = 0; i < F4_PER_THREAD; ++i)
        pv[i] = __builtin_nontemporal_load(&p4[blk_f4 + i * BLOCK + tid]);
#pragma unroll
    for (int i = 0; i < F4_PER_THREAD; ++i)
        tv[i] = __builtin_nontemporal_load(&t4[blk_f4 + i * BLOCK + tid]);

    // ---- Phase 2: linear vector stage into LDS (conflict-free b128) ----
#pragma unroll
    for (int i = 0; i < F4_PER_THREAD; ++i)
        sa[i * BLOCK + tid] = pv[i];
#pragma unroll
    for (int i = 0; i < F4_PER_THREAD; ++i)
        sb[i * BLOCK + tid] = tv[i];

    // global dot term straight from registers (no row structure needed)
    float dot = 0.0f;
#pragma unroll
    for (int i = 0; i < F4_PER_THREAD; ++i)
#pragma unroll
        for (int c = 0; c < 4; ++c)
            dot = fmaf(tv[i][c], pv[i][c], dot);

    __syncthreads();

    // ---- Phase 3: read back 2 whole rows per thread (5x b128 each) ----
    const v4f* ra = reinterpret_cast<const v4f*>(
        reinterpret_cast<const float*>(sa) + 20 * tid);   // byte 80*tid, 16B-aligned
    const v4f* rb = reinterpret_cast<const v4f*>(
        reinterpret_cast<const float*>(sb) + 20 * tid);

    float x[2 * C_DIM], t[2 * C_DIM];
#pragma unroll
    for (int i = 0; i < F4_PER_THREAD; ++i) {
        v4f a = ra[i];
        v4f b = rb[i];
#pragma unroll
        for (int c = 0; c < 4; ++c) {
            x[i * 4 + c] = a[c];
            t[i * 4 + c] = b[c];
        }
    }

    // per-row lse and target-sum, entirely in registers
    float acc = -dot;
#pragma unroll
    for (int half = 0; half < 2; ++half) {
        const int o = half * C_DIM;
        float m = x[o];
#pragma unroll
        for (int y = 1; y < C_DIM; ++y) m = fmaxf(m, x[o + y]);
        float s = 0.0f;
#pragma unroll
        for (int y = 0; y < C_DIM; ++y) s += __expf(x[o + y] - m);
        float st = 0.0f;
#pragma unroll
        for (int y = 0; y < C_DIM; ++y) st += t[o + y];
        acc = fmaf(st, m + __logf(s), acc);
    }

    // ---- Epilogue: wave shuffle -> one store per wave, no barrier ----
#pragma unroll
    for (int off = 32; off > 0; off >>= 1)
        acc += __shfl_down(acc, off, 64);

    if ((tid & 63) == 0)
        partial[blockIdx.x * 4 + (tid >> 6)] = acc;
}

// ---------------- final reduce: one block over NPARTIAL partials ----------------
__global__ __launch_bounds__(RBLOCK) void kl_reduce_kernel(
    const float* __restrict__ partial,
    float* __restrict__ out)
{
    __shared__ float sred[RBLOCK / 64];
    const int tid = threadIdx.x;

    float acc = 0.0f;
#pragma unroll
    for (int i = 0; i < NPARTIAL / RBLOCK; ++i)
        acc += partial[i * RBLOCK + tid];

#pragma unroll
    for (int off = 32; off > 0; off >>= 1)
        acc += __shfl_down(acc, off, 64);

    const int lane = tid & 63;
    const int wid  = tid >> 6;
    if (lane == 0) sred[wid] = acc;
    __syncthreads();

    if (tid == 0) {
        float b = 0.0f;
#pragma unroll
        for (int i = 0; i < RBLOCK / 64; ++i) b += sred[i];
        out[0] = b * (1.0f / (float)N_ROWS);
    }
}

extern "C" void kernel_launch(void* const* d_in, const int* in_sizes, int n_in,
                              void* d_out, int out_size, void* d_ws, size_t ws_size,
                              hipStream_t stream)
{
    const float* pred = (const float*)d_in[0];
    const float* tgt  = (const float*)d_in[1];
    float* out = (float*)d_out;
    float* partialbuf = (float*)d_ws;   // 128 KB used

    kl_loss_kernel<<<NBLOCKS, BLOCK, 0, stream>>>(pred, tgt, partialbuf);
    kl_reduce_kernel<<<1, RBLOCK, 0, stream>>>(partialbuf, out);
}